// Round 3
// baseline (912.487 us; speedup 1.0000x reference)
//
#include <hip/hip_runtime.h>
#include <hip/hip_bf16.h>
#include <stdint.h>

#define BB 2
#define SS 2048
#define DD 2048
#define HH 16
#define HD 128
#define FFD 8192
#define TD (3*DD)

typedef unsigned short u16;
typedef __attribute__((ext_vector_type(8))) short s16x8;
typedef __attribute__((ext_vector_type(4))) float f32x4;

struct alignas(8) U16x4 { u16 a, b, c, d; };

__device__ __forceinline__ u16 f2b(float f) {
  union { float f; uint32_t u; } v; v.f = f;
  uint32_t r = (v.u + 0x7fffu + ((v.u >> 16) & 1u)) >> 16;
  return (u16)r;
}

__device__ __forceinline__ void async16(const void* g, void* l) {
  __builtin_amdgcn_global_load_lds((const __attribute__((address_space(1))) void*)g,
                                   (__attribute__((address_space(3))) void*)l,
                                   16, 0, 0);
}

// ---------------- fused fp32->bf16 transpose-convert:  Wt[N][K] = bf16(W[K][N]) ---
__global__ __launch_bounds__(256) void wconv_t(const float* __restrict__ W,
                                               u16* __restrict__ Wt, int K, int N) {
  __shared__ float tile[64][65];
  int k0 = blockIdx.x * 64, n0 = blockIdx.y * 64;
  int c = threadIdx.x & 63, r0 = threadIdx.x >> 6;
#pragma unroll
  for (int i = 0; i < 16; ++i) {
    int r = i * 4 + r0;
    tile[r][c] = W[(size_t)(k0 + r) * N + n0 + c];
  }
  __syncthreads();
#pragma unroll
  for (int i = 0; i < 16; ++i) {
    int n = i * 4 + r0;
    Wt[(size_t)(n0 + n) * K + k0 + c] = f2b(tile[c][n]);
  }
}

// ---------------- layernorm: fp32 in -> bf16 out, one block per row (D=2048) ------
__global__ __launch_bounds__(256) void ln_kernel(const float* __restrict__ X,
                                                 const float* __restrict__ g,
                                                 const float* __restrict__ be,
                                                 u16* __restrict__ O) {
  int row = blockIdx.x;
  const float* xr = X + (size_t)row * DD;
  int t = threadIdx.x;
  float4 v0 = ((const float4*)xr)[t];
  float4 v1 = ((const float4*)xr)[t + 256];
  float s = v0.x + v0.y + v0.z + v0.w + v1.x + v1.y + v1.z + v1.w;
  float q = v0.x*v0.x + v0.y*v0.y + v0.z*v0.z + v0.w*v0.w
          + v1.x*v1.x + v1.y*v1.y + v1.z*v1.z + v1.w*v1.w;
#pragma unroll
  for (int o = 32; o > 0; o >>= 1) { s += __shfl_down(s, o); q += __shfl_down(q, o); }
  __shared__ float red[8];
  if ((t & 63) == 0) { red[t >> 6] = s; red[4 + (t >> 6)] = q; }
  __syncthreads();
  float S = red[0] + red[1] + red[2] + red[3];
  float Q = red[4] + red[5] + red[6] + red[7];
  float mu = S * (1.0f / DD);
  float var = Q * (1.0f / DD) - mu * mu;
  float rs = rsqrtf(var + 1e-5f);
  float4 g0 = ((const float4*)g)[t],  g1 = ((const float4*)g)[t + 256];
  float4 b0 = ((const float4*)be)[t], b1 = ((const float4*)be)[t + 256];
  U16x4 o0, o1;
  o0.a = f2b((v0.x - mu) * rs * g0.x + b0.x);
  o0.b = f2b((v0.y - mu) * rs * g0.y + b0.y);
  o0.c = f2b((v0.z - mu) * rs * g0.z + b0.z);
  o0.d = f2b((v0.w - mu) * rs * g0.w + b0.w);
  o1.a = f2b((v1.x - mu) * rs * g1.x + b1.x);
  o1.b = f2b((v1.y - mu) * rs * g1.y + b1.y);
  o1.c = f2b((v1.z - mu) * rs * g1.z + b1.z);
  o1.d = f2b((v1.w - mu) * rs * g1.w + b1.w);
  *(U16x4*)(O + (size_t)row * DD + t * 4)         = o0;
  *(U16x4*)(O + (size_t)row * DD + (t + 256) * 4) = o1;
}

// ---------------- 8-wave 256x128 GEMM: C[M,N] = A[M,K](bf16) * Bt[N,K]^T + bias ----
// 512 threads (8 waves, 4 along M x 2 along N). BK=64 as two 32-wide k-halves.
// LDS ring: [parity][khalf] chunks (A: 256x32, B: 128x32). Staging via
// global_load_lds w=16; k-slot XOR pre-swizzle on the GLOBAL address (LDS dest
// stays linear = base + tid*16B); read side applies the same XOR (2-way alias
// on read = free). Counted vmcnt(3) per phase (never 0 in steady state): the
// retained newest-3 are the group just issued; the group read by the NEXT
// phase was retired one phase earlier, two barriers upstream.
// MODE 0: +bias -> bf16 ; MODE 1: +bias,gelu -> bf16 ; MODE 2: +bias,+res -> fp32
template <int MODE>
__global__ __launch_bounds__(512, 2) void gemm8(const u16* __restrict__ A,
                                                const u16* __restrict__ Bt,
                                                const float* __restrict__ bias,
                                                const float* __restrict__ res,
                                                void* __restrict__ Cout,
                                                int M, int N, int K) {
  __shared__ __align__(16) u16 As[2][2][256 * 32];   // 64 KiB
  __shared__ __align__(16) u16 Bs[2][2][128 * 32];   // 32 KiB

  int n0 = blockIdx.x * 128, m0 = blockIdx.y * 256;
  int tid = threadIdx.x;
  int lane = tid & 63, w = tid >> 6;
  int wn = w & 1, wm = w >> 1;
  int col = lane & 15, quad = lane >> 4;

  // staging geometry: thread covers row r = tid>>2, 16B slot sl = tid&3.
  // LDS[r][sl] <- global k-slot (sl ^ ((r>>1)&3))
  int r = tid >> 2, sl = tid & 3;
  int gks = (sl ^ ((r >> 1) & 3)) * 8;
  const u16* ag = A  + (size_t)(m0 + r) * K + gks;
  const u16* bg = Bt + (size_t)(n0 + r) * K + gks;

  int swz = (col >> 1) & 3;            // == (lds_row>>1)&3 for all frag rows
  int aoff = (wm * 64) * 32 + col * 32 + ((quad ^ swz) * 8);
  int boff = (wn * 64) * 32 + col * 32 + ((quad ^ swz) * 8);

  f32x4 acc[4][4] = {};
  int ntiles = K >> 6;

  // ---- prologue: stage tile 0 fully, drain once ----
#pragma unroll
  for (int kh = 0; kh < 2; ++kh) {
    async16(ag + kh * 32, &As[0][kh][tid * 8]);
    async16(ag + (size_t)128 * K + kh * 32, &As[0][kh][4096 + tid * 8]);
    async16(bg + kh * 32, &Bs[0][kh][tid * 8]);
  }
  asm volatile("s_waitcnt vmcnt(0)" ::: "memory");
  __builtin_amdgcn_s_barrier();

  for (int t = 0; t < ntiles; ++t) {
    int p = t & 1, pn = p ^ 1;
    const u16* agn = ag + (t + 1) * 64;
    const u16* bgn = bg + (t + 1) * 64;
    bool pf = (t + 1 < ntiles);
#pragma unroll
    for (int kh = 0; kh < 2; ++kh) {
      const u16* as_ = As[p][kh];
      const u16* bs_ = Bs[p][kh];
      s16x8 af[4], bf[4];
#pragma unroll
      for (int i = 0; i < 4; ++i)
        bf[i] = *(const s16x8*)&bs_[boff + i * 512];
#pragma unroll
      for (int i = 0; i < 4; ++i)
        af[i] = *(const s16x8*)&as_[aoff + i * 512];
      if (pf) {
        async16(agn + kh * 32, &As[pn][kh][tid * 8]);
        async16(agn + (size_t)128 * K + kh * 32, &As[pn][kh][4096 + tid * 8]);
        async16(bgn + kh * 32, &Bs[pn][kh][tid * 8]);
        asm volatile("s_waitcnt vmcnt(3)" ::: "memory");
      } else if (kh == 0) {
        asm volatile("s_waitcnt vmcnt(0)" ::: "memory");  // tail drain, once
      }
      __builtin_amdgcn_s_barrier();
      __builtin_amdgcn_s_setprio(1);
#pragma unroll
      for (int i = 0; i < 4; ++i)
#pragma unroll
        for (int j = 0; j < 4; ++j)
          acc[i][j] = __builtin_amdgcn_mfma_f32_16x16x32_bf16(
              af[i], bf[j], acc[i][j], 0, 0, 0);
      __builtin_amdgcn_s_setprio(0);
      __builtin_amdgcn_s_barrier();
    }
  }

  // ---- epilogue ----
#pragma unroll
  for (int mt = 0; mt < 4; ++mt) {
    int mg = m0 + wm * 64 + mt * 16 + quad * 4;
#pragma unroll
    for (int nt = 0; nt < 4; ++nt) {
      int ng = n0 + wn * 64 + nt * 16 + col;
      float bn = bias[ng];
#pragma unroll
      for (int rr = 0; rr < 4; ++rr) {
        float v = acc[mt][nt][rr] + bn;
        size_t idx = (size_t)(mg + rr) * N + ng;
        if (MODE == 1) {
          // gelu(v) = v * sigmoid(2*0.7978845608*(v + 0.044715 v^3))
          float u = 1.5957691216057308f * (v + 0.044715f * v * v * v);
          v = v / (1.0f + __expf(-u));
        }
        if (MODE == 2) {
          ((float*)Cout)[idx] = v + res[idx];
        } else {
          ((u16*)Cout)[idx] = f2b(v);
        }
      }
    }
  }
}

// ---------------- flash attention with ALiBi + causal --------------------------
// grid: (16, H, B); block 256 (4 waves). Block bx handles q-tiles bx and 31-bx.
__global__ __launch_bounds__(256) void attn_kernel(const u16* __restrict__ qkv,
                                                   u16* __restrict__ out) {
  __shared__ __align__(16) u16 Ks[2][64 * 128];   // [key][hd-slot^swz]
  __shared__ __align__(16) u16 Vts[128 * 64];     // [hd][key^swz]
  __shared__ __align__(16) u16 Ps[4][16 * 72];    // padded stride 72
  int bx = blockIdx.x, h = blockIdx.y, b = blockIdx.z;
  int tid = threadIdx.x, lane = tid & 63, w = tid >> 6;
  int col = lane & 15, quad = lane >> 4;
  const u16* base  = qkv + (size_t)b * SS * TD + (size_t)h * HD;
  const u16* kbase = base + DD;
  const u16* vbase = base + 2 * DD;
  float slope = exp2f(-0.5f * (float)(h + 1));
  const float scale = 0.088388347648318447f;  // 1/sqrt(128)
  int krow = tid >> 4;
  int ghb = (tid & 15) ^ (krow & 7);
  int vkey_loc = tid >> 4;
  int vhd0 = (tid & 15) * 8;
  int kxc = 8 * (tid & 7);

#pragma unroll 1
  for (int ph = 0; ph < 2; ++ph) {
    int qt = ph ? (31 - bx) : bx;
    int q0 = qt * 64;
    int ntile = qt + 1;
    int qr = q0 + w * 16 + col;
    s16x8 qf[4];
#pragma unroll
    for (int c = 0; c < 4; ++c)
      qf[c] = *(const s16x8*)(base + (size_t)qr * TD + c * 32 + quad * 8);
    float m_i[4] = {-1e30f, -1e30f, -1e30f, -1e30f};
    float l_i[4] = {0.f, 0.f, 0.f, 0.f};
    f32x4 oacc[8] = {};
#pragma unroll
    for (int s = 0; s < 4; ++s)
      async16(kbase + (size_t)(s * 16 + krow) * TD + ghb * 8,
              &Ks[0][s * 2048 + tid * 8]);
    s16x8 vreg[4];
#pragma unroll
    for (int s = 0; s < 4; ++s)
      vreg[s] = *(const s16x8*)(vbase + (size_t)(s * 16 + vkey_loc) * TD + vhd0);

    for (int t = 0; t < ntile; ++t) {
      int j0 = t * 64;
      __syncthreads();
      if (t + 1 < ntile) {
#pragma unroll
        for (int s = 0; s < 4; ++s)
          async16(kbase + (size_t)(j0 + 64 + s * 16 + krow) * TD + ghb * 8,
                  &Ks[(t + 1) & 1][s * 2048 + tid * 8]);
      }
#pragma unroll
      for (int s = 0; s < 4; ++s) {
        int key = s * 16 + vkey_loc;
#pragma unroll
        for (int j = 0; j < 8; ++j)
          Vts[(vhd0 + j) * 64 + (key ^ kxc)] = (u16)vreg[s][j];
      }
      if (t + 1 < ntile) {
#pragma unroll
        for (int s = 0; s < 4; ++s)
          vreg[s] = *(const s16x8*)(vbase + (size_t)(j0 + 64 + s * 16 + vkey_loc) * TD + vhd0);
      }
      const u16* kt_ = Ks[t & 1];
      f32x4 sc[4];
#pragma unroll
      for (int nt = 0; nt < 4; ++nt) {
        f32x4 s4 = {0.f, 0.f, 0.f, 0.f};
        int key = nt * 16 + col;
        int ksw = col & 7;
#pragma unroll
        for (int c = 0; c < 4; ++c) {
          s16x8 kf = *(const s16x8*)&kt_[key * 128 + (((c * 4 + quad) ^ ksw) * 8)];
          s4 = __builtin_amdgcn_mfma_f32_16x16x32_bf16(qf[c], kf, s4, 0, 0, 0);
        }
        sc[nt] = s4;
      }
      int rb = q0 + w * 16 + quad * 4;
      float p[4][4];
      float mt_[4] = {-1e30f, -1e30f, -1e30f, -1e30f};
#pragma unroll
      for (int nt = 0; nt < 4; ++nt) {
        int j = j0 + nt * 16 + col;
#pragma unroll
        for (int rr = 0; rr < 4; ++rr) {
          float v = sc[nt][rr] * scale + slope * (float)(j - (rb + rr));
          if (j > rb + rr) v = -1e30f;
          p[nt][rr] = v;
          mt_[rr] = fmaxf(mt_[rr], v);
        }
      }
#pragma unroll
      for (int o = 1; o < 16; o <<= 1)
#pragma unroll
        for (int rr = 0; rr < 4; ++rr) mt_[rr] = fmaxf(mt_[rr], __shfl_xor(mt_[rr], o));
      float alpha[4];
#pragma unroll
      for (int rr = 0; rr < 4; ++rr) {
        float mn = fmaxf(m_i[rr], mt_[rr]);
        alpha[rr] = __expf(m_i[rr] - mn);
        m_i[rr] = mn;
      }
      float ls[4] = {0.f, 0.f, 0.f, 0.f};
#pragma unroll
      for (int nt = 0; nt < 4; ++nt)
#pragma unroll
        for (int rr = 0; rr < 4; ++rr) {
          float e = __expf(p[nt][rr] - m_i[rr]);
          p[nt][rr] = e;
          ls[rr] += e;
        }
#pragma unroll
      for (int o = 1; o < 16; o <<= 1)
#pragma unroll
        for (int rr = 0; rr < 4; ++rr) ls[rr] += __shfl_xor(ls[rr], o);
#pragma unroll
      for (int rr = 0; rr < 4; ++rr) l_i[rr] = l_i[rr] * alpha[rr] + ls[rr];
#pragma unroll
      for (int ot = 0; ot < 8; ++ot)
#pragma unroll
        for (int rr = 0; rr < 4; ++rr) oacc[ot][rr] *= alpha[rr];
#pragma unroll
      for (int nt = 0; nt < 4; ++nt)
#pragma unroll
        for (int rr = 0; rr < 4; ++rr)
          Ps[w][(quad * 4 + rr) * 72 + nt * 16 + col] = f2b(p[nt][rr]);
      __syncthreads();
#pragma unroll
      for (int kt = 0; kt < 2; ++kt) {
        s16x8 pf = *(const s16x8*)&Ps[w][col * 72 + kt * 32 + quad * 8];
        int k8 = kt * 32 + quad * 8;
#pragma unroll
        for (int ot = 0; ot < 8; ++ot) {
          int hd = ot * 16 + col;
          int swz = 8 * ((hd >> 3) & 7);
          s16x8 vf = *(const s16x8*)&Vts[hd * 64 + (k8 ^ swz)];
          oacc[ot] = __builtin_amdgcn_mfma_f32_16x16x32_bf16(pf, vf, oacc[ot], 0, 0, 0);
        }
      }
    }
#pragma unroll
    for (int rr = 0; rr < 4; ++rr) l_i[rr] = 1.0f / l_i[rr];
    u16* ob = out + ((size_t)b * SS + q0 + w * 16 + quad * 4) * DD + h * HD;
#pragma unroll
    for (int ot = 0; ot < 8; ++ot)
#pragma unroll
      for (int rr = 0; rr < 4; ++rr)
        ob[(size_t)rr * DD + ot * 16 + col] = f2b(oacc[ot][rr] * l_i[rr]);
  }
}

extern "C" void kernel_launch(void* const* d_in, const int* in_sizes, int n_in,
                              void* d_out, int out_size, void* d_ws, size_t ws_size,
                              hipStream_t stream) {
  const float* x    = (const float*)d_in[0];
  const float* ln1w = (const float*)d_in[1];
  const float* ln1b = (const float*)d_in[2];
  const float* wqkv = (const float*)d_in[3];
  const float* bqkv = (const float*)d_in[4];
  const float* wo   = (const float*)d_in[5];
  const float* bo   = (const float*)d_in[6];
  const float* ln2w = (const float*)d_in[7];
  const float* ln2b = (const float*)d_in[8];
  const float* w1   = (const float*)d_in[9];
  const float* b1   = (const float*)d_in[10];
  const float* w2   = (const float*)d_in[11];
  const float* b2   = (const float*)d_in[12];

  const int M = BB * SS;  // 4096
  char* ws = (char*)d_ws;
  u16*  wt   = (u16*)ws;                                          // 33.55 MB max
  u16*  qkv  = (u16*)(ws + 33554432ull);                          // 50.33 MB
  u16*  cbuf = (u16*)(ws + 33554432ull + 50331648ull);            // 67.11 MB
  float* r1  = (float*)(ws + 33554432ull + 50331648ull + 67108864ull);  // 33.55 MB
  u16* h1 = cbuf;
  u16* attn = cbuf;
  u16* m1 = cbuf;
  u16* h2 = qkv;

  ln_kernel<<<M, 256, 0, stream>>>(x, ln1w, ln1b, h1);
  wconv_t<<<dim3(DD / 64, TD / 64), 256, 0, stream>>>(wqkv, wt, DD, TD);
  // QKV: N=6144 -> 48x16 = 768 blocks = 3 exact rounds of 256 CUs
  gemm8<0><<<dim3(TD / 128, M / 256), 512, 0, stream>>>(h1, wt, bqkv, nullptr, qkv, M, TD, DD);
  attn_kernel<<<dim3(16, HH, BB), 256, 0, stream>>>(qkv, attn);
  wconv_t<<<dim3(DD / 64, DD / 64), 256, 0, stream>>>(wo, wt, DD, DD);
  // WO: N=2048 -> 16x16 = 256 blocks = 1 exact round
  gemm8<2><<<dim3(DD / 128, M / 256), 512, 0, stream>>>(attn, wt, bo, x, r1, M, DD, DD);
  ln_kernel<<<M, 256, 0, stream>>>(r1, ln2w, ln2b, h2);
  wconv_t<<<dim3(DD / 64, FFD / 64), 256, 0, stream>>>(w1, wt, DD, FFD);
  // W1: N=8192 -> 64x16 = 1024 blocks = 4 exact rounds
  gemm8<1><<<dim3(FFD / 128, M / 256), 512, 0, stream>>>(h2, wt, b1, nullptr, m1, M, FFD, DD);
  wconv_t<<<dim3(FFD / 64, DD / 64), 256, 0, stream>>>(w2, wt, FFD, DD);
  // W2: N=2048, K=8192 -> 256 blocks = 1 exact round
  gemm8<2><<<dim3(DD / 128, M / 256), 512, 0, stream>>>(m1, wt, b2, r1, (float*)d_out, M, DD, FFD);
}

// Round 4
// 854.632 us; speedup vs baseline: 1.0677x; 1.0677x over previous
//
#include <hip/hip_runtime.h>
#include <hip/hip_bf16.h>
#include <stdint.h>

#define BB 2
#define SS 2048
#define DD 2048
#define HH 16
#define HD 128
#define FFD 8192
#define TD (3*DD)

typedef unsigned short u16;
typedef __attribute__((ext_vector_type(8))) short s16x8;
typedef __attribute__((ext_vector_type(4))) float f32x4;

struct alignas(8) U16x4 { u16 a, b, c, d; };

__device__ __forceinline__ u16 f2b(float f) {
  union { float f; uint32_t u; } v; v.f = f;
  uint32_t r = (v.u + 0x7fffu + ((v.u >> 16) & 1u)) >> 16;
  return (u16)r;
}

__device__ __forceinline__ void async16(const void* g, void* l) {
  __builtin_amdgcn_global_load_lds((const __attribute__((address_space(1))) void*)g,
                                   (__attribute__((address_space(3))) void*)l,
                                   16, 0, 0);
}

// ---------------- fused fp32->bf16 transpose-convert:  Wt[N][K] = bf16(W[K][N]) ---
__global__ __launch_bounds__(256) void wconv_t(const float* __restrict__ W,
                                               u16* __restrict__ Wt, int K, int N) {
  __shared__ float tile[64][65];
  int k0 = blockIdx.x * 64, n0 = blockIdx.y * 64;
  int c = threadIdx.x & 63, r0 = threadIdx.x >> 6;
#pragma unroll
  for (int i = 0; i < 16; ++i) {
    int r = i * 4 + r0;
    tile[r][c] = W[(size_t)(k0 + r) * N + n0 + c];
  }
  __syncthreads();
#pragma unroll
  for (int i = 0; i < 16; ++i) {
    int n = i * 4 + r0;
    Wt[(size_t)(n0 + n) * K + k0 + c] = f2b(tile[c][n]);
  }
}

// ---------------- layernorm: fp32 in -> bf16 out, one block per row (D=2048) ------
__global__ __launch_bounds__(256) void ln_kernel(const float* __restrict__ X,
                                                 const float* __restrict__ g,
                                                 const float* __restrict__ be,
                                                 u16* __restrict__ O) {
  int row = blockIdx.x;
  const float* xr = X + (size_t)row * DD;
  int t = threadIdx.x;
  float4 v0 = ((const float4*)xr)[t];
  float4 v1 = ((const float4*)xr)[t + 256];
  float s = v0.x + v0.y + v0.z + v0.w + v1.x + v1.y + v1.z + v1.w;
  float q = v0.x*v0.x + v0.y*v0.y + v0.z*v0.z + v0.w*v0.w
          + v1.x*v1.x + v1.y*v1.y + v1.z*v1.z + v1.w*v1.w;
#pragma unroll
  for (int o = 32; o > 0; o >>= 1) { s += __shfl_down(s, o); q += __shfl_down(q, o); }
  __shared__ float red[8];
  if ((t & 63) == 0) { red[t >> 6] = s; red[4 + (t >> 6)] = q; }
  __syncthreads();
  float S = red[0] + red[1] + red[2] + red[3];
  float Q = red[4] + red[5] + red[6] + red[7];
  float mu = S * (1.0f / DD);
  float var = Q * (1.0f / DD) - mu * mu;
  float rs = rsqrtf(var + 1e-5f);
  float4 g0 = ((const float4*)g)[t],  g1 = ((const float4*)g)[t + 256];
  float4 b0 = ((const float4*)be)[t], b1 = ((const float4*)be)[t + 256];
  U16x4 o0, o1;
  o0.a = f2b((v0.x - mu) * rs * g0.x + b0.x);
  o0.b = f2b((v0.y - mu) * rs * g0.y + b0.y);
  o0.c = f2b((v0.z - mu) * rs * g0.z + b0.z);
  o0.d = f2b((v0.w - mu) * rs * g0.w + b0.w);
  o1.a = f2b((v1.x - mu) * rs * g1.x + b1.x);
  o1.b = f2b((v1.y - mu) * rs * g1.y + b1.y);
  o1.c = f2b((v1.z - mu) * rs * g1.z + b1.z);
  o1.d = f2b((v1.w - mu) * rs * g1.w + b1.w);
  *(U16x4*)(O + (size_t)row * DD + t * 4)         = o0;
  *(U16x4*)(O + (size_t)row * DD + (t + 256) * 4) = o1;
}

// ---------------- 8-wave 256x128 GEMM (proven): used for WO / W2 ------------------
// MODE 0: +bias -> bf16 ; MODE 1: +bias,gelu -> bf16 ; MODE 2: +bias,+res -> fp32
template <int MODE>
__global__ __launch_bounds__(512, 2) void gemm8(const u16* __restrict__ A,
                                                const u16* __restrict__ Bt,
                                                const float* __restrict__ bias,
                                                const float* __restrict__ res,
                                                void* __restrict__ Cout,
                                                int M, int N, int K) {
  __shared__ __align__(16) u16 As[2][2][256 * 32];   // 64 KiB
  __shared__ __align__(16) u16 Bs[2][2][128 * 32];   // 32 KiB

  int n0 = blockIdx.x * 128, m0 = blockIdx.y * 256;
  int tid = threadIdx.x;
  int lane = tid & 63, w = tid >> 6;
  int wn = w & 1, wm = w >> 1;
  int col = lane & 15, quad = lane >> 4;

  int r = tid >> 2, sl = tid & 3;
  int gks = (sl ^ ((r >> 1) & 3)) * 8;
  const u16* ag = A  + (size_t)(m0 + r) * K + gks;
  const u16* bg = Bt + (size_t)(n0 + r) * K + gks;

  int swz = (col >> 1) & 3;
  int aoff = (wm * 64) * 32 + col * 32 + ((quad ^ swz) * 8);
  int boff = (wn * 64) * 32 + col * 32 + ((quad ^ swz) * 8);

  f32x4 acc[4][4] = {};
  int ntiles = K >> 6;

#pragma unroll
  for (int kh = 0; kh < 2; ++kh) {
    async16(ag + kh * 32, &As[0][kh][tid * 8]);
    async16(ag + (size_t)128 * K + kh * 32, &As[0][kh][4096 + tid * 8]);
    async16(bg + kh * 32, &Bs[0][kh][tid * 8]);
  }
  asm volatile("s_waitcnt vmcnt(0)" ::: "memory");
  __builtin_amdgcn_s_barrier();

  for (int t = 0; t < ntiles; ++t) {
    int p = t & 1, pn = p ^ 1;
    const u16* agn = ag + (t + 1) * 64;
    const u16* bgn = bg + (t + 1) * 64;
    bool pf = (t + 1 < ntiles);
#pragma unroll
    for (int kh = 0; kh < 2; ++kh) {
      const u16* as_ = As[p][kh];
      const u16* bs_ = Bs[p][kh];
      s16x8 af[4], bf[4];
#pragma unroll
      for (int i = 0; i < 4; ++i)
        bf[i] = *(const s16x8*)&bs_[boff + i * 512];
#pragma unroll
      for (int i = 0; i < 4; ++i)
        af[i] = *(const s16x8*)&as_[aoff + i * 512];
      if (pf) {
        async16(agn + kh * 32, &As[pn][kh][tid * 8]);
        async16(agn + (size_t)128 * K + kh * 32, &As[pn][kh][4096 + tid * 8]);
        async16(bgn + kh * 32, &Bs[pn][kh][tid * 8]);
        asm volatile("s_waitcnt vmcnt(3)" ::: "memory");
      } else if (kh == 0) {
        asm volatile("s_waitcnt vmcnt(0)" ::: "memory");
      }
      __builtin_amdgcn_s_barrier();
      __builtin_amdgcn_s_setprio(1);
#pragma unroll
      for (int i = 0; i < 4; ++i)
#pragma unroll
        for (int j = 0; j < 4; ++j)
          acc[i][j] = __builtin_amdgcn_mfma_f32_16x16x32_bf16(
              af[i], bf[j], acc[i][j], 0, 0, 0);
      __builtin_amdgcn_s_setprio(0);
      __builtin_amdgcn_s_barrier();
    }
  }

#pragma unroll
  for (int mt = 0; mt < 4; ++mt) {
    int mg = m0 + wm * 64 + mt * 16 + quad * 4;
#pragma unroll
    for (int nt = 0; nt < 4; ++nt) {
      int ng = n0 + wn * 64 + nt * 16 + col;
      float bn = bias[ng];
#pragma unroll
      for (int rr = 0; rr < 4; ++rr) {
        float v = acc[mt][nt][rr] + bn;
        size_t idx = (size_t)(mg + rr) * N + ng;
        if (MODE == 1) {
          float u = 1.5957691216057308f * (v + 0.044715f * v * v * v);
          v = v / (1.0f + __expf(-u));
        }
        if (MODE == 2) {
          ((float*)Cout)[idx] = v + res[idx];
        } else {
          ((u16*)Cout)[idx] = f2b(v);
        }
      }
    }
  }
}

// ---------------- 256x256 m201-geometry GEMM: used for QKV / W1 -------------------
// 512 threads = 8 waves (2 along M x 4 along N); per-wave output 128x64 (8m x 4n).
// BK=64 as two 32-wide k-halves; 4 phases per K-tile = (khalf, m-quadrant):
//   phase: { ds_read af[4] (+bf[4] at q==0, held across the k-half);
//            stage 2 global_load_lds of tile t+1 (order A[kh0],B[kh0],A[kh1],B[kh1]);
//            vmcnt(4) at q==1 only;  barrier;  setprio(1); 16 MFMA; setprio(0); barrier }
// FIFO ledger (2 loads/phase): at t-ph1's vmcnt(4) the retained newest-4 are
// A[kh1],B[kh1] of tile t; the retired oldest are A[kh0],B[kh0] of tile t — read
// two barriers later at t+1-ph0. WAR: a buffer is overwritten >=2 barriers after
// its last read. Last tile: single vmcnt(0) at ph1 (4 loads of tile t-1 in flight).
// LDS 128 KiB: As/Bs[buf][khalf][256*32], XOR k-slot swizzle as gemm8 (verified 0-conflict).
template <int MODE>
__global__ __launch_bounds__(512, 2) void gemm256(const u16* __restrict__ A,
                                                  const u16* __restrict__ Bt,
                                                  const float* __restrict__ bias,
                                                  const float* __restrict__ res,
                                                  void* __restrict__ Cout,
                                                  int M, int N, int K) {
  __shared__ __align__(16) u16 As[2][2][256 * 32];   // 64 KiB
  __shared__ __align__(16) u16 Bs[2][2][256 * 32];   // 64 KiB

  int n0 = blockIdx.x * 256, m0 = blockIdx.y * 256;
  int tid = threadIdx.x;
  int lane = tid & 63, w = tid >> 6;
  int wn = w & 3, wm = w >> 2;
  int col = lane & 15, quad = lane >> 4;

  // staging: thread covers LDS row r=tid>>2 (and r+128 in group 1), slot sl=tid&3;
  // fetches global k-slot sl^((r>>1)&3)  (key invariant under +128: 64 = 0 mod 4)
  int r = tid >> 2, sl = tid & 3;
  int gks = (sl ^ ((r >> 1) & 3)) * 8;
  const u16* ag = A  + (size_t)(m0 + r) * K + gks;
  const u16* bg = Bt + (size_t)(n0 + r) * K + gks;

  int swz = (col >> 1) & 3;            // row&... == (col>>1)&3 for all frag rows
  int aoff = (wm * 128 + col) * 32 + ((quad ^ swz) * 8);
  int boff = (wn * 64 + col) * 32 + ((quad ^ swz) * 8);

  f32x4 acc[8][4] = {};
  int ntiles = K >> 6;

  // ---- prologue: stage tile 0 fully (8 loads/thread), drain once ----
#pragma unroll
  for (int kh = 0; kh < 2; ++kh) {
    async16(ag + kh * 32, &As[0][kh][tid * 8]);
    async16(ag + (size_t)128 * K + kh * 32, &As[0][kh][4096 + tid * 8]);
    async16(bg + kh * 32, &Bs[0][kh][tid * 8]);
    async16(bg + (size_t)128 * K + kh * 32, &Bs[0][kh][4096 + tid * 8]);
  }
  asm volatile("s_waitcnt vmcnt(0)" ::: "memory");
  __builtin_amdgcn_s_barrier();

  for (int t = 0; t < ntiles; ++t) {
    int p = t & 1, pn = p ^ 1;
    const u16* agn = ag + (t + 1) * 64;
    const u16* bgn = bg + (t + 1) * 64;
    bool pf = (t + 1 < ntiles);
#pragma unroll
    for (int kh = 0; kh < 2; ++kh) {
      const u16* as_ = As[p][kh];
      const u16* bs_ = Bs[p][kh];
      s16x8 bf[4];
#pragma unroll
      for (int j = 0; j < 4; ++j)
        bf[j] = *(const s16x8*)&bs_[boff + j * 512];
#pragma unroll
      for (int q = 0; q < 2; ++q) {
        s16x8 af[4];
#pragma unroll
        for (int i = 0; i < 4; ++i)
          af[i] = *(const s16x8*)&as_[aoff + q * 2048 + i * 512];
        if (pf) {
          if (q == 0) {       // stage A-half-tiles for k-half kh of tile t+1
            async16(agn + kh * 32, &As[pn][kh][tid * 8]);
            async16(agn + (size_t)128 * K + kh * 32, &As[pn][kh][4096 + tid * 8]);
          } else {            // stage B-half-tiles for k-half kh of tile t+1
            async16(bgn + kh * 32, &Bs[pn][kh][tid * 8]);
            async16(bgn + (size_t)128 * K + kh * 32, &Bs[pn][kh][4096 + tid * 8]);
            asm volatile("s_waitcnt vmcnt(4)" ::: "memory");
          }
        } else if (kh == 0 && q == 1) {
          asm volatile("s_waitcnt vmcnt(0)" ::: "memory");  // tail drain, once
        }
        __builtin_amdgcn_s_barrier();
        __builtin_amdgcn_s_setprio(1);
#pragma unroll
        for (int i = 0; i < 4; ++i)
#pragma unroll
          for (int j = 0; j < 4; ++j)
            acc[q * 4 + i][j] = __builtin_amdgcn_mfma_f32_16x16x32_bf16(
                af[i], bf[j], acc[q * 4 + i][j], 0, 0, 0);
        __builtin_amdgcn_s_setprio(0);
        __builtin_amdgcn_s_barrier();
      }
    }
  }

  // ---- epilogue ----
#pragma unroll
  for (int mt = 0; mt < 8; ++mt) {
    int mg = m0 + wm * 128 + mt * 16 + quad * 4;
#pragma unroll
    for (int nt = 0; nt < 4; ++nt) {
      int ng = n0 + wn * 64 + nt * 16 + col;
      float bn = bias[ng];
#pragma unroll
      for (int rr = 0; rr < 4; ++rr) {
        float v = acc[mt][nt][rr] + bn;
        size_t idx = (size_t)(mg + rr) * N + ng;
        if (MODE == 1) {
          // gelu(v) = v * sigmoid(2*0.7978845608*(v + 0.044715 v^3))
          float u = 1.5957691216057308f * (v + 0.044715f * v * v * v);
          v = v / (1.0f + __expf(-u));
        }
        if (MODE == 2) {
          ((float*)Cout)[idx] = v + res[idx];
        } else {
          ((u16*)Cout)[idx] = f2b(v);
        }
      }
    }
  }
}

// ---------------- flash attention with ALiBi + causal --------------------------
// grid: (16, H, B); block 256 (4 waves). Block bx handles q-tiles bx and 31-bx.
__global__ __launch_bounds__(256) void attn_kernel(const u16* __restrict__ qkv,
                                                   u16* __restrict__ out) {
  __shared__ __align__(16) u16 Ks[2][64 * 128];   // [key][hd-slot^swz]
  __shared__ __align__(16) u16 Vts[128 * 64];     // [hd][key^swz]
  __shared__ __align__(16) u16 Ps[4][16 * 72];    // padded stride 72
  int bx = blockIdx.x, h = blockIdx.y, b = blockIdx.z;
  int tid = threadIdx.x, lane = tid & 63, w = tid >> 6;
  int col = lane & 15, quad = lane >> 4;
  const u16* base  = qkv + (size_t)b * SS * TD + (size_t)h * HD;
  const u16* kbase = base + DD;
  const u16* vbase = base + 2 * DD;
  float slope = exp2f(-0.5f * (float)(h + 1));
  const float scale = 0.088388347648318447f;  // 1/sqrt(128)
  int krow = tid >> 4;
  int ghb = (tid & 15) ^ (krow & 7);
  int vkey_loc = tid >> 4;
  int vhd0 = (tid & 15) * 8;
  int kxc = 8 * (tid & 7);

#pragma unroll 1
  for (int ph = 0; ph < 2; ++ph) {
    int qt = ph ? (31 - bx) : bx;
    int q0 = qt * 64;
    int ntile = qt + 1;
    int qr = q0 + w * 16 + col;
    s16x8 qf[4];
#pragma unroll
    for (int c = 0; c < 4; ++c)
      qf[c] = *(const s16x8*)(base + (size_t)qr * TD + c * 32 + quad * 8);
    float m_i[4] = {-1e30f, -1e30f, -1e30f, -1e30f};
    float l_i[4] = {0.f, 0.f, 0.f, 0.f};
    f32x4 oacc[8] = {};
#pragma unroll
    for (int s = 0; s < 4; ++s)
      async16(kbase + (size_t)(s * 16 + krow) * TD + ghb * 8,
              &Ks[0][s * 2048 + tid * 8]);
    s16x8 vreg[4];
#pragma unroll
    for (int s = 0; s < 4; ++s)
      vreg[s] = *(const s16x8*)(vbase + (size_t)(s * 16 + vkey_loc) * TD + vhd0);

    for (int t = 0; t < ntile; ++t) {
      int j0 = t * 64;
      __syncthreads();
      if (t + 1 < ntile) {
#pragma unroll
        for (int s = 0; s < 4; ++s)
          async16(kbase + (size_t)(j0 + 64 + s * 16 + krow) * TD + ghb * 8,
                  &Ks[(t + 1) & 1][s * 2048 + tid * 8]);
      }
#pragma unroll
      for (int s = 0; s < 4; ++s) {
        int key = s * 16 + vkey_loc;
#pragma unroll
        for (int j = 0; j < 8; ++j)
          Vts[(vhd0 + j) * 64 + (key ^ kxc)] = (u16)vreg[s][j];
      }
      if (t + 1 < ntile) {
#pragma unroll
        for (int s = 0; s < 4; ++s)
          vreg[s] = *(const s16x8*)(vbase + (size_t)(j0 + 64 + s * 16 + vkey_loc) * TD + vhd0);
      }
      const u16* kt_ = Ks[t & 1];
      f32x4 sc[4];
#pragma unroll
      for (int nt = 0; nt < 4; ++nt) {
        f32x4 s4 = {0.f, 0.f, 0.f, 0.f};
        int key = nt * 16 + col;
        int ksw = col & 7;
#pragma unroll
        for (int c = 0; c < 4; ++c) {
          s16x8 kf = *(const s16x8*)&kt_[key * 128 + (((c * 4 + quad) ^ ksw) * 8)];
          s4 = __builtin_amdgcn_mfma_f32_16x16x32_bf16(qf[c], kf, s4, 0, 0, 0);
        }
        sc[nt] = s4;
      }
      int rb = q0 + w * 16 + quad * 4;
      float p[4][4];
      float mt_[4] = {-1e30f, -1e30f, -1e30f, -1e30f};
#pragma unroll
      for (int nt = 0; nt < 4; ++nt) {
        int j = j0 + nt * 16 + col;
#pragma unroll
        for (int rr = 0; rr < 4; ++rr) {
          float v = sc[nt][rr] * scale + slope * (float)(j - (rb + rr));
          if (j > rb + rr) v = -1e30f;
          p[nt][rr] = v;
          mt_[rr] = fmaxf(mt_[rr], v);
        }
      }
#pragma unroll
      for (int o = 1; o < 16; o <<= 1)
#pragma unroll
        for (int rr = 0; rr < 4; ++rr) mt_[rr] = fmaxf(mt_[rr], __shfl_xor(mt_[rr], o));
      float alpha[4];
#pragma unroll
      for (int rr = 0; rr < 4; ++rr) {
        float mn = fmaxf(m_i[rr], mt_[rr]);
        alpha[rr] = __expf(m_i[rr] - mn);
        m_i[rr] = mn;
      }
      float ls[4] = {0.f, 0.f, 0.f, 0.f};
#pragma unroll
      for (int nt = 0; nt < 4; ++nt)
#pragma unroll
        for (int rr = 0; rr < 4; ++rr) {
          float e = __expf(p[nt][rr] - m_i[rr]);
          p[nt][rr] = e;
          ls[rr] += e;
        }
#pragma unroll
      for (int o = 1; o < 16; o <<= 1)
#pragma unroll
        for (int rr = 0; rr < 4; ++rr) ls[rr] += __shfl_xor(ls[rr], o);
#pragma unroll
      for (int rr = 0; rr < 4; ++rr) l_i[rr] = l_i[rr] * alpha[rr] + ls[rr];
#pragma unroll
      for (int ot = 0; ot < 8; ++ot)
#pragma unroll
        for (int rr = 0; rr < 4; ++rr) oacc[ot][rr] *= alpha[rr];
#pragma unroll
      for (int nt = 0; nt < 4; ++nt)
#pragma unroll
        for (int rr = 0; rr < 4; ++rr)
          Ps[w][(quad * 4 + rr) * 72 + nt * 16 + col] = f2b(p[nt][rr]);
      __syncthreads();
#pragma unroll
      for (int kt = 0; kt < 2; ++kt) {
        s16x8 pf = *(const s16x8*)&Ps[w][col * 72 + kt * 32 + quad * 8];
        int k8 = kt * 32 + quad * 8;
#pragma unroll
        for (int ot = 0; ot < 8; ++ot) {
          int hd = ot * 16 + col;
          int swz = 8 * ((hd >> 3) & 7);
          s16x8 vf = *(const s16x8*)&Vts[hd * 64 + (k8 ^ swz)];
          oacc[ot] = __builtin_amdgcn_mfma_f32_16x16x32_bf16(pf, vf, oacc[ot], 0, 0, 0);
        }
      }
    }
#pragma unroll
    for (int rr = 0; rr < 4; ++rr) l_i[rr] = 1.0f / l_i[rr];
    u16* ob = out + ((size_t)b * SS + q0 + w * 16 + quad * 4) * DD + h * HD;
#pragma unroll
    for (int ot = 0; ot < 8; ++ot)
#pragma unroll
      for (int rr = 0; rr < 4; ++rr)
        ob[(size_t)rr * DD + ot * 16 + col] = f2b(oacc[ot][rr] * l_i[rr]);
  }
}

extern "C" void kernel_launch(void* const* d_in, const int* in_sizes, int n_in,
                              void* d_out, int out_size, void* d_ws, size_t ws_size,
                              hipStream_t stream) {
  const float* x    = (const float*)d_in[0];
  const float* ln1w = (const float*)d_in[1];
  const float* ln1b = (const float*)d_in[2];
  const float* wqkv = (const float*)d_in[3];
  const float* bqkv = (const float*)d_in[4];
  const float* wo   = (const float*)d_in[5];
  const float* bo   = (const float*)d_in[6];
  const float* ln2w = (const float*)d_in[7];
  const float* ln2b = (const float*)d_in[8];
  const float* w1   = (const float*)d_in[9];
  const float* b1   = (const float*)d_in[10];
  const float* w2   = (const float*)d_in[11];
  const float* b2   = (const float*)d_in[12];

  const int M = BB * SS;  // 4096
  char* ws = (char*)d_ws;
  u16*  wt   = (u16*)ws;                                          // 33.55 MB max
  u16*  qkv  = (u16*)(ws + 33554432ull);                          // 50.33 MB
  u16*  cbuf = (u16*)(ws + 33554432ull + 50331648ull);            // 67.11 MB
  float* r1  = (float*)(ws + 33554432ull + 50331648ull + 67108864ull);  // 33.55 MB
  u16* h1 = cbuf;
  u16* attn = cbuf;
  u16* m1 = cbuf;
  u16* h2 = qkv;

  ln_kernel<<<M, 256, 0, stream>>>(x, ln1w, ln1b, h1);
  wconv_t<<<dim3(DD / 64, TD / 64), 256, 0, stream>>>(wqkv, wt, DD, TD);
  // QKV: N=6144 -> 24x16 = 384 blocks (1.5 rounds) at 256^2 geometry
  gemm256<0><<<dim3(TD / 256, M / 256), 512, 0, stream>>>(h1, wt, bqkv, nullptr, qkv, M, TD, DD);
  attn_kernel<<<dim3(16, HH, BB), 256, 0, stream>>>(qkv, attn);
  wconv_t<<<dim3(DD / 64, DD / 64), 256, 0, stream>>>(wo, wt, DD, DD);
  // WO: N=2048 -> 256^2 would give only 128 blocks (half the CUs idle) -> keep gemm8
  gemm8<2><<<dim3(DD / 128, M / 256), 512, 0, stream>>>(attn, wt, bo, x, r1, M, DD, DD);
  ln_kernel<<<M, 256, 0, stream>>>(r1, ln2w, ln2b, h2);
  wconv_t<<<dim3(DD / 64, FFD / 64), 256, 0, stream>>>(w1, wt, DD, FFD);
  // W1: N=8192 -> 32x16 = 512 blocks = 2 exact rounds at 256^2 geometry
  gemm256<1><<<dim3(FFD / 256, M / 256), 512, 0, stream>>>(h2, wt, b1, nullptr, m1, M, FFD, DD);
  wconv_t<<<dim3(FFD / 64, DD / 64), 256, 0, stream>>>(w2, wt, FFD, DD);
  // W2: N=2048, K=8192 -> keep gemm8 (256 blocks = 1 exact round)
  gemm8<2><<<dim3(DD / 128, M / 256), 512, 0, stream>>>(m1, wt, b2, r1, (float*)d_out, M, DD, FFD);
}